// Round 3
// 378.635 us; speedup vs baseline: 1.0092x; 1.0092x over previous
//
#include <hip/hip_runtime.h>
#include <math.h>

#define TQ 2000   // T_OUT (scan dim)
#define TK 400    // T_IN  (key/class dim)
#define NB 64     // batch = scan blocks

// ---- scan geometry: 4 waves/block, 2 adjacent pairs per lane (packed f32) ----
#define WSC 4     // scan waves per block (waves 4..7 are barrier-idlers)
#define EP 102    // owned pairs per wave (4*102 = 408 >= 401)
#define HHALF 13  // steps per per-wave rescale half-group
#define GS 26     // steps per halo-sync group (= halo depth in pairs)
#define PF 26     // prefetch ring depth (rows ahead)

// ---- lse role (unchanged from verified baseline) ----
#define NLSE 192  // lse blocks
#define WPB 24    // lse waves per batch (192*8/64)
#define RPW 84    // rows per lse wave (24*84 >= 2000)

typedef unsigned long long u64;
typedef float f32x2 __attribute__((ext_vector_type(2)));

__device__ __forceinline__ float ex2(float x) { return __builtin_amdgcn_exp2f(x); }
__device__ __forceinline__ float lg2(float x) { return __builtin_amdgcn_logf(x); }  // log2

#define L2E 1.4426950408889634f
#define LN2f 0.6931471805599453f
#define EB 0.36787944117144233f  // e^-1 (unnormalized blank emission)

__device__ __forceinline__ f32x2 mk2(float a, float b) {
  f32x2 r; r.x = a; r.y = b; return r;
}

// lane l gets lane l-1's value; lane 0 gets `fill` (bound_ctrl=false, old=fill)
__device__ __forceinline__ float dpp_shr1_wave(float v, float fill) {
  return __int_as_float(__builtin_amdgcn_update_dpp(
      __float_as_int(fill), __float_as_int(v), 0x138 /*wave_shr:1*/, 0xF, 0xF,
      false));
}
template <int CTRL, int RM>
__device__ __forceinline__ float dpp_mv(float v) {
  return __int_as_float(__builtin_amdgcn_update_dpp(
      0, __float_as_int(v), CTRL, RM, 0xF, true));  // invalid lanes -> 0
}
__device__ __forceinline__ float wave_sum_dpp(float s) {
  s = s + dpp_mv<0x111, 0xF>(s);  // row_shr:1
  s = s + dpp_mv<0x112, 0xF>(s);  // row_shr:2
  s = s + dpp_mv<0x114, 0xF>(s);  // row_shr:4
  s = s + dpp_mv<0x118, 0xF>(s);  // row_shr:8
  s = s + dpp_mv<0x142, 0xA>(s);  // row_bcast:15
  s = s + dpp_mv<0x143, 0xC>(s);  // row_bcast:31 -> lane 63 = total
  return s;
}
// max of NON-NEGATIVE values (0-fill is identity); total in lane 63
__device__ __forceinline__ float wave_max_dpp(float s) {
  s = fmaxf(s, dpp_mv<0x111, 0xF>(s));
  s = fmaxf(s, dpp_mv<0x112, 0xF>(s));
  s = fmaxf(s, dpp_mv<0x114, 0xF>(s));
  s = fmaxf(s, dpp_mv<0x118, 0xF>(s));
  s = fmaxf(s, dpp_mv<0x142, 0xA>(s));
  s = fmaxf(s, dpp_mv<0x143, 0xC>(s));
  return s;
}

union F2U {
  f32x2 f;
  u64 u;
};

// ---------------------------------------------------------------------------
// Kernel A, grid = 256 x 512 (1 block/CU):
//  blocks 0..63   : linear-domain CTC forward scan, 4 waves x 2 pairs/lane
//                   (native f32x2 vector ops -> compiler emits v_pk_*_f32 with
//                   DPP hazards modeled; NO inline-asm VALU, which defeated the
//                   hazard recognizer in the previous revision),
//                   per-wave rescale (no barrier) every 13 steps,
//                   cross-wave halo exchange every 26 steps (77 barriers max).
//                   Scale merge is direction-aware: only factors <= 1 applied.
//                   Waves 4..7 idle but match the s_barrier count exactly.
//  blocks 64..255 : per-row softmax denominators -> Cpart partials (unchanged).
// Kernel B (tiny) combines.
// ---------------------------------------------------------------------------
__global__ __launch_bounds__(512) void fusedA_kernel(
    const float* __restrict__ attn, const int* __restrict__ in_lens,
    const int* __restrict__ out_lens, float* __restrict__ Cpart,
    float* __restrict__ Sres) {
  const int bid = blockIdx.x;
  const int tid = threadIdx.x;
  const int w = tid >> 6, l = tid & 63;

  if (bid >= NB) {
    // ---------------- LSE role (verified baseline, unchanged) ----------------
    const int W = (bid - NB) * 8 + w;  // 0..1535
    const int b = W / WPB;
    const int chunk = W - b * WPB;
    const int in_len = in_lens[b];
    const int out_len = out_lens[b];
    const int start = chunk * RPW;
    const int endr = min(min(start + RPW, TQ), out_len);
    const float4* base = (const float4*)(attn + (size_t)b * TQ * TK);
    const bool has2 = (l + 64) < 100;  // 100 float4 per row
    const int c1i = l, c2i = has2 ? (l + 64) : 35;
    const int b1 = l * 4, b2 = (l + 64) * 4;
    float acc = 0.0f;
    const int live = endr - start;
    float4 c1, c2;
    if (live > 0) {
      const float4* rp = base + (size_t)start * 100;
      c1 = rp[c1i];
      c2 = rp[c2i];
    }
    for (int i = 0; i < live; ++i) {
      float4 n1, n2;
      if (i + 1 < live) {  // prefetch next row
        const float4* rp = base + (size_t)(start + i + 1) * 100;
        n1 = rp[c1i];
        n2 = rp[c2i];
      }
      float e1a[4] = {c1.x, c1.y, c1.z, c1.w};
      float e2a[4] = {c2.x, c2.y, c2.z, c2.w};
      float s = 0.0f;
#pragma unroll
      for (int e = 0; e < 4; ++e) {
        s += (b1 + e < in_len) ? ex2(e1a[e] * L2E) : 0.0f;
        s += (has2 && (b2 + e < in_len)) ? ex2(e2a[e] * L2E) : 0.0f;
      }
      s = wave_sum_dpp(s);  // lane 63 = row sum
      acc += lg2(s + EB);   // meaningful on lane 63 only
      c1 = n1;
      c2 = n2;
    }
    if (l == 63) Cpart[b * WPB + chunk] = acc * LN2f;  // natural-log partial
    return;
  }

  // ---------------- scan role ----------------
  const int b = bid;
  const int in_len = in_lens[b];
  const int out_len = out_lens[b];
  const int ngroups = (out_len - 2) / GS + 1;  // = ceil((out_len-1)/GS)

  __shared__ u64 H[2][WSC][HHALF][2];        // halo: 2 pairs/lane as 2x u64
  __shared__ __align__(8) float Wls[2][WSC]; // per-wave lsum at sync
  __shared__ float Af0[WSC * EP + 8];
  __shared__ float Af1[WSC * EP + 8];
  __shared__ float LsF[WSC];

  if (w >= WSC) {
    // barrier-idler: match scan waves' s_barrier count exactly, then the
    // final __syncthreads. Keeps s_barrier semantics defined for 512 threads.
    for (int g = 0; g < ngroups; ++g) __builtin_amdgcn_s_barrier();
    __syncthreads();
    return;
  }

  const float* __restrict__ arow = attn + (size_t)b * TQ * TK;
  // lane l of wave w holds pairs (p0, p0+1); low 13 lanes (26 pairs) are halo
  const int p0 = EP * w - GS + 2 * l;  // even
  const int p1 = p0 + 1;
  const int cL = min(max(p0, 0), TK - 2);  // even -> 8B-aligned float2 loads
  const f32x2 c_msk = mk2((p0 >= 0 && p0 < in_len) ? 1.0f : 0.0f,
                          (p1 >= 0 && p1 < in_len) ? 1.0f : 0.0f);

  f32x2 A0 = mk2(0.0f, 0.0f);  // blank states (2*p0, 2*p1)
  f32x2 A1 = mk2(0.0f, 0.0f);  // token states (2*p0+1, 2*p1+1)
  {
    const float x00 = arow[cL];
    if (p0 == 0) {  // wave 0, lane 13 owns pair 0
      A0.x = EB;
      A1.x = ex2(x00 * L2E);
    }
  }
  float lsum = 0.0f;  // log2 of accumulated inverse scale (per-wave uniform)
  bool mzero = true;  // wave was all-zero at last rescale checkpoint

  f32x2 xq[PF];
#pragma unroll
  for (int j = 0; j < PF; ++j)
    xq[j] = *(const f32x2*)(arow + (size_t)(1 + j) * TK + cL);

#define STEP(SLOT, TCUR, PRED)                                        \
  {                                                                   \
    const f32x2 x = xq[SLOT];                                         \
    const int rown = ((TCUR) + PF < TQ) ? ((TCUR) + PF) : (TQ - 1);   \
    xq[SLOT] = *(const f32x2*)(arow + (size_t)rown * TK + cL);        \
    const f32x2 ev = mk2(ex2(x.x * L2E), ex2(x.y * L2E)) * c_msk;     \
    const float left = dpp_shr1_wave(A1.y, 0.0f);                     \
    const f32x2 t2 = A0 + mk2(left, A1.x);                            \
    const f32x2 n1 = (t2 + A1) * ev;                                  \
    const f32x2 n0 = t2 * EB;                                         \
    if (PRED) {                                                       \
      if ((TCUR) < out_len) {  /* block-uniform condition */          \
        A0 = n0;                                                      \
        A1 = n1;                                                      \
      }                                                               \
    } else {                                                          \
      A0 = n0;                                                        \
      A1 = n1;                                                        \
    }                                                                 \
  }

  // per-wave rescale: DPP max + readlane broadcast, no barrier needed
#define RESCALE()                                                     \
  {                                                                   \
    float m4 = fmaxf(fmaxf(A0.x, A0.y), fmaxf(A1.x, A1.y));           \
    float wmx = wave_max_dpp(m4);                                     \
    const float bm = __int_as_float(                                  \
        __builtin_amdgcn_readlane(__float_as_int(wmx), 63));          \
    if (bm > 0.0f) {                                                  \
      const int e = (__float_as_int(bm) >> 23) & 0xff;                \
      const float sc = __int_as_float((254 - e) << 23);               \
      A0 = A0 * sc;                                                   \
      A1 = A1 * sc;                                                   \
      lsum += (float)(e - 127);                                       \
      mzero = false;                                                  \
    } else {                                                          \
      mzero = true;                                                   \
    }                                                                 \
  }

  int hb = 0;
  for (int tb = 1; tb < out_len; tb += GS) {
#pragma unroll
    for (int h = 0; h < 2; ++h) {
      const bool fast = (tb + h * HHALF + HHALF) <= out_len;
      if (fast) {
#pragma unroll
        for (int j = 0; j < HHALF; ++j)
          STEP(h * HHALF + j, tb + h * HHALF + j, 0)
      } else {
#pragma unroll
        for (int j = 0; j < HHALF; ++j)
          STEP(h * HHALF + j, tb + h * HHALF + j, 1)
      }
      RESCALE()
    }
    // halo publish: lanes 51..63 hold this wave's top 26 pairs
    // (reader lane l <-> writer lane l+51, exact index correspondence)
    if (l >= 64 - HHALF) {
      F2U h0, h1;
      h0.f = mk2(A0.x, A1.x);
      h1.f = mk2(A0.y, A1.y);
      volatile u64* hp = (volatile u64*)&H[hb][w][l - (64 - HHALF)][0];
      hp[0] = h0.u;
      hp[1] = h1.u;
    }
    if (l == 63) *(volatile float*)&Wls[hb][w] = lsum;
    asm volatile("s_waitcnt lgkmcnt(0)\ns_barrier");  // lgkm-only, no vm drain
    const int wsrc = (w > 0) ? (w - 1) : 0;
    const int lidx = (l < HHALF) ? l : 0;
    F2U r0, r1;
    volatile u64* rp = (volatile u64*)&H[hb][wsrc][lidx][0];
    r0.u = rp[0];
    r1.u = rp[1];
    const float Lp = *(volatile float*)&Wls[hb][wsrc];
    if (w > 0) {
      // direction-aware scale reconciliation; only factors <= 1 are applied
      // (underflow == flush-to-zero, identical semantics to block rescale).
      const float delta = Lp - lsum;  // integer-valued, exact in f32
      float sfh;                      // factor applied to incoming halo
      if (mzero) {
        lsum = Lp;  // own values all zero: adopt neighbor's scale
        sfh = 1.0f;
      } else if (delta > 0.0f) {
        // neighbor's scale dominates: shrink own values, adopt its scale
        const float so = ex2(-delta);  // <= 1, underflows gracefully
        A0 = A0 * so;
        A1 = A1 * so;
        lsum = Lp;
        sfh = 1.0f;
      } else {
        sfh = ex2(delta);  // <= 1, underflows gracefully
      }
      if (l < HHALF) {
        A0.x = r0.f.x * sfh;
        A1.x = r0.f.y * sfh;
        A0.y = r1.f.x * sfh;
        A1.y = r1.f.y * sfh;
      }
      RESCALE()  // normalize after merge so next 13 steps can't overflow
    }
    hb ^= 1;
  }
#undef STEP
#undef RESCALE

  // publish final alpha (owned lanes 13..63 cover pairs [EP*w, EP*w+102))
  if (l >= HHALF) {
    Af0[p0] = A0.x;
    Af1[p0] = A1.x;
    Af0[p1] = A0.y;
    Af1[p1] = A1.y;
  }
  if (l == 0) LsF[w] = lsum;
  __syncthreads();
  if (tid == 0) {
    Sres[4 * b + 0] = Af0[in_len];             // a0 at pair in_len (state 2L)
    Sres[4 * b + 1] = LsF[in_len / EP];        // its wave's log2-scale
    Sres[4 * b + 2] = Af1[in_len - 1];         // a1 at pair in_len-1 (state 2L-1)
    Sres[4 * b + 3] = LsF[(in_len - 1) / EP];  // its wave's log2-scale
  }
}

// ---------------------------------------------------------------------------
// Kernel B: combine per-batch pieces, mean over batch. One wave.
// ---------------------------------------------------------------------------
__global__ __launch_bounds__(64) void finalize_kernel(
    const float* __restrict__ Cpart, const float* __restrict__ Sres,
    const int* __restrict__ in_lens, float* __restrict__ out) {
  const int b = threadIdx.x;  // 0..63
  float C = 0.0f;
#pragma unroll
  for (int c = 0; c < WPB; ++c) C += Cpart[b * WPB + c];
  const float v0 = Sres[4 * b + 0];
  const float e0 = Sres[4 * b + 1];
  const float v1 = Sres[4 * b + 2];
  const float e1 = Sres[4 * b + 3];
  float lb = 0.0f;
  if (v0 > 0.0f || v1 > 0.0f) {
    const float l0 = (v0 > 0.0f) ? (lg2(v0) + e0) : -3.0e38f;
    const float l1 = (v1 > 0.0f) ? (lg2(v1) + e1) : -3.0e38f;
    const float mm = fmaxf(l0, l1);
    const float ll2 = mm + lg2(ex2(l0 - mm) + ex2(l1 - mm));  // log2-sum-exp2
    const float ll = ll2 * LN2f - C;  // natural log, softmax-normalized
    lb = -ll / (float)in_lens[b];
    if (!(fabsf(lb) < 1.0e37f)) lb = 0.0f;  // zero_infinity guard
  }
  float v = wave_sum_dpp(lb);
  if (b == 63) out[0] = v * (1.0f / (float)NB);
}

extern "C" void kernel_launch(void* const* d_in, const int* in_sizes, int n_in,
                              void* d_out, int out_size, void* d_ws, size_t ws_size,
                              hipStream_t stream) {
  const float* attn = (const float*)d_in[0];  // (B,1,TQ,TK) f32
  const int* in_lens = (const int*)d_in[1];   // (B,) i32
  const int* out_lens = (const int*)d_in[2];  // (B,) i32
  float* Cpart = (float*)d_ws;                // NB*WPB floats
  float* Sres = Cpart + NB * WPB;             // NB*4 floats
  float* out = (float*)d_out;                 // scalar

  hipLaunchKernelGGL(fusedA_kernel, dim3(NB + NLSE), dim3(512), 0, stream,
                     attn, in_lens, out_lens, Cpart, Sres);
  hipLaunchKernelGGL(finalize_kernel, dim3(1), dim3(64), 0, stream,
                     Cpart, Sres, in_lens, out);
}